// Round 4
// baseline (167.325 us; speedup 1.0000x reference)
//
#include <hip/hip_runtime.h>
#include <hip/hip_bf16.h>

#define B_ 2
#define C_ 256
#define S_ 4096
#define NH 8
#define HD 32
#define EPSV 1e-5f
// QSCALE * log2(e): scores computed in log2 units so softmax uses exp2
#define QSC2 0.25503487942324256f

typedef __bf16 bf16_t;
typedef bf16_t bf16x8 __attribute__((ext_vector_type(8)));
typedef float f32x4 __attribute__((ext_vector_type(4)));
typedef float f32x16 __attribute__((ext_vector_type(16)));
typedef int i32x2 __attribute__((ext_vector_type(2)));
typedef __hip_bfloat16 hbf;

__device__ inline unsigned cvtpk_bf16(float a, float b) {
  unsigned r;
  asm("v_cvt_pk_bf16_f32 %0, %1, %2" : "=v"(r) : "v"(a), "v"(b));
  return r;
}

// ---------------- fp32 -> bf16 weight convert ----------------
__global__ __launch_bounds__(256) void f2bf_kernel(const float* __restrict__ src, hbf* __restrict__ dst, int n) {
  int i = blockIdx.x * 256 + threadIdx.x;
  if (i < n) dst[i] = __float2bfloat16(src[i]);
}

// ---------------- GroupNorm + transpose: x[b][c][s] f32 -> xn_t[b][s][c] bf16 ----------------
__global__ __launch_bounds__(256) void gn_kernel(const float* __restrict__ x, const float* __restrict__ gw,
                                                 const float* __restrict__ gb, hbf* __restrict__ xn_t) {
  int b = blockIdx.x >> 5, g = blockIdx.x & 31;
  const float* xp = x + ((size_t)b * C_ + g * 8) * S_;
  float sum = 0.f, sumsq = 0.f;
  const float4* xp4 = (const float4*)xp;
  for (int i = threadIdx.x; i < 8 * S_ / 4; i += 256) {
    float4 v = xp4[i];
    sum += v.x + v.y + v.z + v.w;
    sumsq += v.x * v.x + v.y * v.y + v.z * v.z + v.w * v.w;
  }
#pragma unroll
  for (int off = 32; off > 0; off >>= 1) {
    sum += __shfl_down(sum, off);
    sumsq += __shfl_down(sumsq, off);
  }
  __shared__ float red[2][4];
  int wid = threadIdx.x >> 6;
  if ((threadIdx.x & 63) == 0) { red[0][wid] = sum; red[1][wid] = sumsq; }
  __syncthreads();
  sum = red[0][0] + red[0][1] + red[0][2] + red[0][3];
  sumsq = red[1][0] + red[1][1] + red[1][2] + red[1][3];
  const float inv_n = 1.f / (8 * S_);
  float mean = sum * inv_n;
  float rstd = rsqrtf(fmaxf(sumsq * inv_n - mean * mean, 0.f) + EPSV);
  int c = threadIdx.x & 7;
  float sc = gw[g * 8 + c] * rstd;
  float sh = gb[g * 8 + c] - mean * sc;
  hbf* outp = xn_t + (size_t)b * S_ * C_ + g * 8;
  for (int i = threadIdx.x; i < 8 * S_; i += 256) {
    int s = i >> 3;
    float v = xp[(size_t)c * S_ + s];
    outp[(size_t)s * C_ + c] = __float2bfloat16(v * sc + sh);
  }
}

// ---------------- QKV GEMM (BT-form): D[s][o] = sum_c xn_t[s][c] * W[o][c] + bias ----------------
// o<256: q -> qbuf[b][s][o] scaled by QSC2
// 256<=o<512: k -> kbuf[b][h][t][d] head-contiguous
// o>=512: v -> vbuf[b][o-512][s] (transposed)
__global__ __launch_bounds__(256) void qkv_gemm(const hbf* __restrict__ xn_t, const hbf* __restrict__ wb,
                                                const float* __restrict__ bias,
                                                hbf* __restrict__ qbuf, hbf* __restrict__ kbuf,
                                                hbf* __restrict__ vbuf) {
  int bt = blockIdx.z;
  int m0 = blockIdx.x * 64;
  int n0 = blockIdx.y * 64;
  const hbf* A = xn_t + (size_t)bt * S_ * C_;
  __shared__ hbf a_lds[64][72];
  __shared__ hbf b_lds[64][72];
  int tid = threadIdx.x, lane = tid & 63, wid = tid >> 6;
  int wm = (wid >> 1) * 32, wn = (wid & 1) * 32;
  f32x4 acc[2][2] = {};
  for (int k0 = 0; k0 < C_; k0 += 64) {
    __syncthreads();
    int r = tid >> 3, kk = (tid & 7) * 8;
#pragma unroll
    for (int p = 0; p < 2; p++) {
      *(bf16x8*)&a_lds[r + p * 32][kk] = *(const bf16x8*)&A[(size_t)(m0 + r + p * 32) * C_ + k0 + kk];
      *(bf16x8*)&b_lds[r + p * 32][kk] = *(const bf16x8*)&wb[(size_t)(n0 + r + p * 32) * C_ + k0 + kk];
    }
    __syncthreads();
#pragma unroll
    for (int kk2 = 0; kk2 < 64; kk2 += 32) {
      bf16x8 af[2], bfr[2];
#pragma unroll
      for (int mi = 0; mi < 2; mi++)
        af[mi] = *(const bf16x8*)&a_lds[wm + mi * 16 + (lane & 15)][kk2 + (lane >> 4) * 8];
#pragma unroll
      for (int ni = 0; ni < 2; ni++)
        bfr[ni] = *(const bf16x8*)&b_lds[wn + ni * 16 + (lane & 15)][kk2 + (lane >> 4) * 8];
#pragma unroll
      for (int mi = 0; mi < 2; mi++)
#pragma unroll
        for (int ni = 0; ni < 2; ni++)
          acc[mi][ni] = __builtin_amdgcn_mfma_f32_16x16x32_bf16(af[mi], bfr[ni], acc[mi][ni], 0, 0, 0);
    }
  }
#pragma unroll
  for (int mi = 0; mi < 2; mi++)
#pragma unroll
    for (int ni = 0; ni < 2; ni++) {
      int o = n0 + wn + ni * 16 + (lane & 15);
      int s = m0 + wm + mi * 16 + (lane >> 4) * 4;
      float bs = bias[o];
      f32x4 v = acc[mi][ni];
      if (o < 256) {
#pragma unroll
        for (int rr = 0; rr < 4; rr++)
          qbuf[((size_t)bt * S_ + s + rr) * C_ + o] = __float2bfloat16((v[rr] + bs) * QSC2);
      } else if (o < 512) {
        int hh = (o - 256) >> 5, dd = (o - 256) & 31;
#pragma unroll
        for (int rr = 0; rr < 4; rr++)
          kbuf[((size_t)(bt * NH + hh) * S_ + s + rr) * HD + dd] = __float2bfloat16(v[rr] + bs);
      } else {
        alignas(8) hbf tmp[4];
#pragma unroll
        for (int rr = 0; rr < 4; rr++) tmp[rr] = __float2bfloat16(v[rr] + bs);
        *(uint2*)&vbuf[((size_t)bt * C_ + (o - 512)) * S_ + s] = *(uint2*)tmp;
      }
    }
}

// ---------------- Flash attention v4: 32x32 MFMA, in-register P via cvt_pk + permlane32_swap ----------------
// Block: 128 q-rows, 4 waves x 32 q. t-tile 128. Swapped QK (sc = D[t][q], col q = lane&31),
// fixed-max exp2, P relayout C-frag -> B-frag fully in registers, PV swapped (A = V_T),
// l via ones-MFMA. K in kbuf[b][h][t][32] (coalesced staging), K/V LDS XOR-swizzled 128B rows.
__global__ __launch_bounds__(256) void attn_kernel(const hbf* __restrict__ qbuf, const hbf* __restrict__ kbuf,
                                                   const hbf* __restrict__ vbuf, hbf* __restrict__ attn_t) {
  int bt = blockIdx.z, h = blockIdx.y;
  int s0 = blockIdx.x * 128;
  const hbf* kbh = kbuf + (size_t)(bt * NH + h) * S_ * HD;
  const hbf* vb = vbuf + ((size_t)bt * C_ + h * HD) * S_;
  int tid = threadIdx.x, lane = tid & 63, w = tid >> 6;
  int l31 = lane & 31, hi = lane >> 5;
  __shared__ hbf k_lds[128 * 64];   // K[t][d], 128B rows (d padded 32->64), 16B-block c ^= (t&7)
  __shared__ hbf v_lds[32 * 128];   // V_T[d][t], 256B rows... 128 bf16 = 256B; block c ^= (d&7)
  // Q B-frags: lane holds Q[q = l31][d = kk*16 + hi*8 + j]  (q pre-scaled by QSC2)
  int qrow = s0 + w * 32 + l31;
  bf16x8 qf0 = *(const bf16x8*)&qbuf[((size_t)bt * S_ + qrow) * C_ + h * HD + hi * 8];
  bf16x8 qf1 = *(const bf16x8*)&qbuf[((size_t)bt * S_ + qrow) * C_ + h * HD + 16 + hi * 8];
  bf16x8 ones;
#pragma unroll
  for (int i = 0; i < 8; i++) ones[i] = (bf16_t)1.0f;
  f32x16 o_acc = {0.f,0.f,0.f,0.f,0.f,0.f,0.f,0.f,0.f,0.f,0.f,0.f,0.f,0.f,0.f,0.f};
  f32x16 l_acc = o_acc;
  const f32x16 z16 = o_acc;
  const int dmask = l31 & 7;
  for (int t0 = 0; t0 < S_; t0 += 128) {
    __syncthreads();
    // stage K: 128 rows x 32 d -> [128][64] swizzled; fully coalesced global reads
#pragma unroll
    for (int p = 0; p < 2; p++) {
      int ci = tid + (p << 8);
      int r = ci >> 2, c = ci & 3;
      *(bf16x8*)&k_lds[(size_t)r * 64 + ((c ^ (r & 7)) << 3)] =
          *(const bf16x8*)&kbh[(size_t)(t0 + r) * HD + (c << 3)];
    }
    // stage V_T: 32 rows x 128 t -> [32][128] swizzled; coalesced
#pragma unroll
    for (int p = 0; p < 2; p++) {
      int ci = tid + (p << 8);
      int d = ci >> 4, c = ci & 15;
      *(bf16x8*)&v_lds[(size_t)d * 128 + ((c ^ (d & 7)) << 3)] =
          *(const bf16x8*)&vb[(size_t)d * S_ + t0 + (c << 3)];
    }
    __syncthreads();
#pragma unroll
    for (int tb = 0; tb < 4; tb++) {
      int t = tb * 32 + l31;
      int tmask = t & 7;
      // QK^T swapped: sc = D[t][q], A = K[t][k], B = Q (2 chained k-blocks over d=32)
      bf16x8 ka0 = *(const bf16x8*)&k_lds[(size_t)t * 64 + (((0 + hi) ^ tmask) << 3)];
      bf16x8 ka1 = *(const bf16x8*)&k_lds[(size_t)t * 64 + (((2 + hi) ^ tmask) << 3)];
      f32x16 sc = __builtin_amdgcn_mfma_f32_32x32x16_bf16(ka0, qf0, z16, 0, 0, 0);
      sc = __builtin_amdgcn_mfma_f32_32x32x16_bf16(ka1, qf1, sc, 0, 0, 0);
      // fixed-max softmax numerator: p = exp2(sc)
#pragma unroll
      for (int i = 0; i < 16; i++) sc[i] = exp2f(sc[i]);
      // C-frag -> B-frag in registers: per 16-t block kb: 4 cvt_pk + 2 permlane32_swap
#pragma unroll
      for (int kb = 0; kb < 2; kb++) {
        unsigned a0 = cvtpk_bf16(sc[kb * 8 + 0], sc[kb * 8 + 1]);
        unsigned b0 = cvtpk_bf16(sc[kb * 8 + 2], sc[kb * 8 + 3]);
        unsigned a1 = cvtpk_bf16(sc[kb * 8 + 4], sc[kb * 8 + 5]);
        unsigned b1 = cvtpk_bf16(sc[kb * 8 + 6], sc[kb * 8 + 7]);
        i32x2 ra = __builtin_amdgcn_permlane32_swap((int)a0, (int)a1, false, false);
        i32x2 rb = __builtin_amdgcn_permlane32_swap((int)b0, (int)b1, false, false);
        union { unsigned u[4]; bf16x8 v; } pf;
        pf.u[0] = (unsigned)ra[0]; pf.u[1] = (unsigned)rb[0];
        pf.u[2] = (unsigned)ra[1]; pf.u[3] = (unsigned)rb[1];
        // l += ones * P ; O_T += V_T * P
        l_acc = __builtin_amdgcn_mfma_f32_32x32x16_bf16(ones, pf.v, l_acc, 0, 0, 0);
        bf16x8 va = *(const bf16x8*)&v_lds[(size_t)l31 * 128 + ((((tb << 2) + (kb << 1) + hi) ^ dmask) << 3)];
        o_acc = __builtin_amdgcn_mfma_f32_32x32x16_bf16(va, pf.v, o_acc, 0, 0, 0);
      }
    }
  }
  float inv_l = 1.0f / l_acc[0];
  // O_T[d][q]: col q = l31 = qrow lane; rows d = (reg&3) + 8*(reg>>2) + 4*hi
#pragma unroll
  for (int c2 = 0; c2 < 4; c2++) {
    alignas(8) hbf tmp[4];
#pragma unroll
    for (int r = 0; r < 4; r++) tmp[r] = __float2bfloat16(o_acc[c2 * 4 + r] * inv_l);
    *(uint2*)&attn_t[((size_t)bt * S_ + qrow) * C_ + h * HD + c2 * 8 + hi * 4] = *(uint2*)tmp;
  }
}

// ---------------- Proj GEMM + bias + residual: out[b][o][s] f32 ----------------
__global__ __launch_bounds__(256) void proj_gemm(const hbf* __restrict__ attn_t, const hbf* __restrict__ wb,
                                                 const float* __restrict__ bias, const float* __restrict__ x,
                                                 float* __restrict__ out) {
  int bt = blockIdx.z;
  int m0 = blockIdx.x * 64;
  int n0 = blockIdx.y * 64;
  const hbf* A = attn_t + (size_t)bt * S_ * C_;
  __shared__ hbf a_lds[64][72];
  __shared__ hbf b_lds[64][72];
  int tid = threadIdx.x, lane = tid & 63, wid = tid >> 6;
  int wm = (wid >> 1) * 32, wn = (wid & 1) * 32;
  f32x4 acc[2][2] = {};
  for (int k0 = 0; k0 < C_; k0 += 64) {
    __syncthreads();
    int r = tid >> 3, kk = (tid & 7) * 8;
#pragma unroll
    for (int p = 0; p < 2; p++) {
      *(bf16x8*)&a_lds[r + p * 32][kk] = *(const bf16x8*)&A[(size_t)(m0 + r + p * 32) * C_ + k0 + kk];
      *(bf16x8*)&b_lds[r + p * 32][kk] = *(const bf16x8*)&wb[(size_t)(n0 + r + p * 32) * C_ + k0 + kk];
    }
    __syncthreads();
#pragma unroll
    for (int kk2 = 0; kk2 < 64; kk2 += 32) {
      bf16x8 af[2], bfr[2];
#pragma unroll
      for (int mi = 0; mi < 2; mi++)
        af[mi] = *(const bf16x8*)&a_lds[wm + mi * 16 + (lane & 15)][kk2 + (lane >> 4) * 8];
#pragma unroll
      for (int ni = 0; ni < 2; ni++)
        bfr[ni] = *(const bf16x8*)&b_lds[wn + ni * 16 + (lane & 15)][kk2 + (lane >> 4) * 8];
#pragma unroll
      for (int mi = 0; mi < 2; mi++)
#pragma unroll
        for (int ni = 0; ni < 2; ni++)
          acc[mi][ni] = __builtin_amdgcn_mfma_f32_16x16x32_bf16(af[mi], bfr[ni], acc[mi][ni], 0, 0, 0);
    }
  }
#pragma unroll
  for (int mi = 0; mi < 2; mi++)
#pragma unroll
    for (int ni = 0; ni < 2; ni++) {
      int o = n0 + wn + ni * 16 + (lane & 15);
      int s = m0 + wm + mi * 16 + (lane >> 4) * 4;
      size_t base = ((size_t)bt * C_ + o) * S_ + s;
      float pb = bias[o];
      float4 xr = *(const float4*)&x[base];
      float4 res;
      res.x = acc[mi][ni][0] + pb + xr.x;
      res.y = acc[mi][ni][1] + pb + xr.y;
      res.z = acc[mi][ni][2] + pb + xr.z;
      res.w = acc[mi][ni][3] + pb + xr.w;
      *(float4*)&out[base] = res;
    }
}

extern "C" void kernel_launch(void* const* d_in, const int* in_sizes, int n_in,
                              void* d_out, int out_size, void* d_ws, size_t ws_size,
                              hipStream_t stream) {
  const float* x = (const float*)d_in[0];
  const float* gn_w = (const float*)d_in[1];
  const float* gn_b = (const float*)d_in[2];
  const float* qkv_w = (const float*)d_in[3];
  const float* qkv_b = (const float*)d_in[4];
  const float* proj_w = (const float*)d_in[5];
  const float* proj_b = (const float*)d_in[6];
  float* out = (float*)d_out;

  hbf* qkv_w_bf = (hbf*)d_ws;                                   // 768*256
  hbf* proj_w_bf = qkv_w_bf + 768 * 256;                        // 256*256
  hbf* xn_t = proj_w_bf + 256 * 256;                            // B*S*C
  hbf* qbuf = xn_t + (size_t)B_ * S_ * C_;                      // B*S*C (q, scaled)
  hbf* kbuf = qbuf + (size_t)B_ * S_ * C_;                      // B*NH*S*HD (k head-contiguous)
  hbf* vbuf = kbuf + (size_t)B_ * S_ * C_;                      // B*C*S (v transposed per head)
  hbf* attn_t = vbuf + (size_t)B_ * C_ * S_;                    // B*S*C

  dim3 blk(256);
  f2bf_kernel<<<(768 * 256 + 255) / 256, blk, 0, stream>>>(qkv_w, qkv_w_bf, 768 * 256);
  f2bf_kernel<<<(256 * 256 + 255) / 256, blk, 0, stream>>>(proj_w, proj_w_bf, 256 * 256);
  gn_kernel<<<64, blk, 0, stream>>>(x, gn_w, gn_b, xn_t);
  qkv_gemm<<<dim3(64, 12, 2), blk, 0, stream>>>(xn_t, qkv_w_bf, qkv_b, qbuf, kbuf, vbuf);
  attn_kernel<<<dim3(32, 8, 2), blk, 0, stream>>>(qbuf, kbuf, vbuf, attn_t);
  proj_gemm<<<dim3(64, 4, 2), blk, 0, stream>>>(attn_t, proj_w_bf, proj_b, x, out);
}

// Round 5
// 144.031 us; speedup vs baseline: 1.1617x; 1.1617x over previous
//
#include <hip/hip_runtime.h>
#include <hip/hip_bf16.h>

#define B_ 2
#define C_ 256
#define S_ 4096
#define NH 8
#define HD 32
#define EPSV 1e-5f
// QSCALE * log2(e): scores computed in log2 units so softmax uses exp2
#define QSC2 0.25503487942324256f

typedef __bf16 bf16_t;
typedef bf16_t bf16x8 __attribute__((ext_vector_type(8)));
typedef float f32x4 __attribute__((ext_vector_type(4)));
typedef float f32x16 __attribute__((ext_vector_type(16)));
typedef int i32x2 __attribute__((ext_vector_type(2)));
typedef __hip_bfloat16 hbf;

__device__ inline unsigned cvtpk_bf16(float a, float b) {
  unsigned r;
  asm("v_cvt_pk_bf16_f32 %0, %1, %2" : "=v"(r) : "v"(a), "v"(b));
  return r;
}

// ---------------- fp32 -> bf16 weight convert ----------------
__global__ __launch_bounds__(256) void f2bf_kernel(const float* __restrict__ src, hbf* __restrict__ dst, int n) {
  int i = blockIdx.x * 256 + threadIdx.x;
  if (i < n) dst[i] = __float2bfloat16(src[i]);
}

// ---------------- GroupNorm + transpose: x[b][c][s] f32 -> xn_t[b][s][c] bf16 ----------------
__global__ __launch_bounds__(256) void gn_kernel(const float* __restrict__ x, const float* __restrict__ gw,
                                                 const float* __restrict__ gb, hbf* __restrict__ xn_t) {
  int b = blockIdx.x >> 5, g = blockIdx.x & 31;
  const float* xp = x + ((size_t)b * C_ + g * 8) * S_;
  float sum = 0.f, sumsq = 0.f;
  const float4* xp4 = (const float4*)xp;
  for (int i = threadIdx.x; i < 8 * S_ / 4; i += 256) {
    float4 v = xp4[i];
    sum += v.x + v.y + v.z + v.w;
    sumsq += v.x * v.x + v.y * v.y + v.z * v.z + v.w * v.w;
  }
#pragma unroll
  for (int off = 32; off > 0; off >>= 1) {
    sum += __shfl_down(sum, off);
    sumsq += __shfl_down(sumsq, off);
  }
  __shared__ float red[2][4];
  int wid = threadIdx.x >> 6;
  if ((threadIdx.x & 63) == 0) { red[0][wid] = sum; red[1][wid] = sumsq; }
  __syncthreads();
  sum = red[0][0] + red[0][1] + red[0][2] + red[0][3];
  sumsq = red[1][0] + red[1][1] + red[1][2] + red[1][3];
  const float inv_n = 1.f / (8 * S_);
  float mean = sum * inv_n;
  float rstd = rsqrtf(fmaxf(sumsq * inv_n - mean * mean, 0.f) + EPSV);
  int c = threadIdx.x & 7;
  float sc = gw[g * 8 + c] * rstd;
  float sh = gb[g * 8 + c] - mean * sc;
  hbf* outp = xn_t + (size_t)b * S_ * C_ + g * 8;
  for (int i = threadIdx.x; i < 8 * S_; i += 256) {
    int s = i >> 3;
    float v = xp[(size_t)c * S_ + s];
    outp[(size_t)s * C_ + c] = __float2bfloat16(v * sc + sh);
  }
}

// ---------------- QKV GEMM (BT-form): D[s][o] = sum_c xn_t[s][c] * W[o][c] + bias ----------------
// o<256: q -> qbuf[b][s][o] scaled by QSC2
// 256<=o<512: k -> kbuf[b][h][t][d] head-contiguous
// o>=512: v -> vbuf[b][o-512][s] (transposed)
__global__ __launch_bounds__(256) void qkv_gemm(const hbf* __restrict__ xn_t, const hbf* __restrict__ wb,
                                                const float* __restrict__ bias,
                                                hbf* __restrict__ qbuf, hbf* __restrict__ kbuf,
                                                hbf* __restrict__ vbuf) {
  int bt = blockIdx.z;
  int m0 = blockIdx.x * 64;
  int n0 = blockIdx.y * 64;
  const hbf* A = xn_t + (size_t)bt * S_ * C_;
  __shared__ hbf a_lds[64][72];
  __shared__ hbf b_lds[64][72];
  int tid = threadIdx.x, lane = tid & 63, wid = tid >> 6;
  int wm = (wid >> 1) * 32, wn = (wid & 1) * 32;
  f32x4 acc[2][2] = {};
  for (int k0 = 0; k0 < C_; k0 += 64) {
    __syncthreads();
    int r = tid >> 3, kk = (tid & 7) * 8;
#pragma unroll
    for (int p = 0; p < 2; p++) {
      *(bf16x8*)&a_lds[r + p * 32][kk] = *(const bf16x8*)&A[(size_t)(m0 + r + p * 32) * C_ + k0 + kk];
      *(bf16x8*)&b_lds[r + p * 32][kk] = *(const bf16x8*)&wb[(size_t)(n0 + r + p * 32) * C_ + k0 + kk];
    }
    __syncthreads();
#pragma unroll
    for (int kk2 = 0; kk2 < 64; kk2 += 32) {
      bf16x8 af[2], bfr[2];
#pragma unroll
      for (int mi = 0; mi < 2; mi++)
        af[mi] = *(const bf16x8*)&a_lds[wm + mi * 16 + (lane & 15)][kk2 + (lane >> 4) * 8];
#pragma unroll
      for (int ni = 0; ni < 2; ni++)
        bfr[ni] = *(const bf16x8*)&b_lds[wn + ni * 16 + (lane & 15)][kk2 + (lane >> 4) * 8];
#pragma unroll
      for (int mi = 0; mi < 2; mi++)
#pragma unroll
        for (int ni = 0; ni < 2; ni++)
          acc[mi][ni] = __builtin_amdgcn_mfma_f32_16x16x32_bf16(af[mi], bfr[ni], acc[mi][ni], 0, 0, 0);
    }
  }
#pragma unroll
  for (int mi = 0; mi < 2; mi++)
#pragma unroll
    for (int ni = 0; ni < 2; ni++) {
      int o = n0 + wn + ni * 16 + (lane & 15);
      int s = m0 + wm + mi * 16 + (lane >> 4) * 4;
      float bs = bias[o];
      f32x4 v = acc[mi][ni];
      if (o < 256) {
#pragma unroll
        for (int rr = 0; rr < 4; rr++)
          qbuf[((size_t)bt * S_ + s + rr) * C_ + o] = __float2bfloat16((v[rr] + bs) * QSC2);
      } else if (o < 512) {
        int hh = (o - 256) >> 5, dd = (o - 256) & 31;
#pragma unroll
        for (int rr = 0; rr < 4; rr++)
          kbuf[((size_t)(bt * NH + hh) * S_ + s + rr) * HD + dd] = __float2bfloat16(v[rr] + bs);
      } else {
        alignas(8) hbf tmp[4];
#pragma unroll
        for (int rr = 0; rr < 4; rr++) tmp[rr] = __float2bfloat16(v[rr] + bs);
        *(uint2*)&vbuf[((size_t)bt * C_ + (o - 512)) * S_ + s] = *(uint2*)tmp;
      }
    }
}

// ---------------- Flash attention v5: v4 math + 8-wave blocks (4 q-subtiles x 2 t-halves) ----------------
// Block: 512 threads. QBLK=128 q-rows (4 waves x 32 q), t split in 2 halves across wave groups.
// Per iteration stage a 256-t super-tile; wave (wq,wt) consumes its 128-t half.
// Fixed-max softmax => t-halves combine by pure addition of (o_acc, l_acc) at the end via LDS.
__global__ __launch_bounds__(512, 4) void attn_kernel(const hbf* __restrict__ qbuf, const hbf* __restrict__ kbuf,
                                                      const hbf* __restrict__ vbuf, hbf* __restrict__ attn_t) {
  int bt = blockIdx.z, h = blockIdx.y;
  int s0 = blockIdx.x * 128;
  const hbf* kbh = kbuf + (size_t)(bt * NH + h) * S_ * HD;
  const hbf* vb = vbuf + ((size_t)bt * C_ + h * HD) * S_;
  int tid = threadIdx.x, lane = tid & 63, w = tid >> 6;
  int wq = w & 3, wt = w >> 2;
  int l31 = lane & 31, hi = lane >> 5;
  __shared__ char smem[49152];
  hbf* k_lds = (hbf*)smem;            // K[t][d]: 256 rows x 64 (d padded 32->64), 16B-block c ^= (t&7)  [32KB]
  hbf* v_lds = (hbf*)(smem + 32768);  // V_T[d][t]: 32 rows x 256, 16B-block c ^= (d&7)                  [16KB]
  f32x16* ored = (f32x16*)smem;       // epilogue overlay: per-lane o_acc of wt=1 waves [16KB]
  float* lred = (float*)(smem + 16384);  // epilogue overlay: l of wt=1 waves [1KB]
  // Q B-frags: lane holds Q[q = l31][d = kk*16 + hi*8 + j]  (q pre-scaled by QSC2)
  int qrow = s0 + wq * 32 + l31;
  bf16x8 qf0 = *(const bf16x8*)&qbuf[((size_t)bt * S_ + qrow) * C_ + h * HD + hi * 8];
  bf16x8 qf1 = *(const bf16x8*)&qbuf[((size_t)bt * S_ + qrow) * C_ + h * HD + 16 + hi * 8];
  bf16x8 ones;
#pragma unroll
  for (int i = 0; i < 8; i++) ones[i] = (bf16_t)1.0f;
  f32x16 o_acc = {0.f,0.f,0.f,0.f,0.f,0.f,0.f,0.f,0.f,0.f,0.f,0.f,0.f,0.f,0.f,0.f};
  f32x16 l_acc = o_acc;
  const f32x16 z16 = o_acc;
  const int dmask = l31 & 7;
  const int rbase = wt * 128;  // this wave's t-half within the staged 256-t super-tile
  for (int t0 = 0; t0 < S_; t0 += 256) {
    __syncthreads();
    // stage K: 256 rows x 32 d -> [256][64] swizzled; fully coalesced global reads
#pragma unroll
    for (int p = 0; p < 2; p++) {
      int ci = tid + (p << 9);
      int r = ci >> 2, c = ci & 3;
      *(bf16x8*)&k_lds[(size_t)r * 64 + ((c ^ (r & 7)) << 3)] =
          *(const bf16x8*)&kbh[(size_t)(t0 + r) * HD + (c << 3)];
    }
    // stage V_T: 32 rows x 256 t -> [32][256] swizzled; coalesced
#pragma unroll
    for (int p = 0; p < 2; p++) {
      int ci = tid + (p << 9);
      int d = ci >> 5, c = ci & 31;
      *(bf16x8*)&v_lds[(size_t)d * 256 + ((c ^ (d & 7)) << 3)] =
          *(const bf16x8*)&vb[(size_t)d * S_ + t0 + (c << 3)];
    }
    __syncthreads();
#pragma unroll
    for (int tb = 0; tb < 4; tb++) {
      int t = rbase + tb * 32 + l31;
      int tmask = t & 7;
      // QK^T swapped: sc = D[t][q], A = K[t][k], B = Q (2 chained k-blocks over d=32)
      bf16x8 ka0 = *(const bf16x8*)&k_lds[(size_t)t * 64 + (((0 + hi) ^ tmask) << 3)];
      bf16x8 ka1 = *(const bf16x8*)&k_lds[(size_t)t * 64 + (((2 + hi) ^ tmask) << 3)];
      f32x16 sc = __builtin_amdgcn_mfma_f32_32x32x16_bf16(ka0, qf0, z16, 0, 0, 0);
      sc = __builtin_amdgcn_mfma_f32_32x32x16_bf16(ka1, qf1, sc, 0, 0, 0);
      // fixed-max softmax numerator: p = exp2(sc)
#pragma unroll
      for (int i = 0; i < 16; i++) sc[i] = exp2f(sc[i]);
      // C-frag -> B-frag in registers: per 16-t block kb: 4 cvt_pk + 2 permlane32_swap
#pragma unroll
      for (int kb = 0; kb < 2; kb++) {
        unsigned a0 = cvtpk_bf16(sc[kb * 8 + 0], sc[kb * 8 + 1]);
        unsigned b0 = cvtpk_bf16(sc[kb * 8 + 2], sc[kb * 8 + 3]);
        unsigned a1 = cvtpk_bf16(sc[kb * 8 + 4], sc[kb * 8 + 5]);
        unsigned b1 = cvtpk_bf16(sc[kb * 8 + 6], sc[kb * 8 + 7]);
        i32x2 ra = __builtin_amdgcn_permlane32_swap((int)a0, (int)a1, false, false);
        i32x2 rb = __builtin_amdgcn_permlane32_swap((int)b0, (int)b1, false, false);
        union { unsigned u[4]; bf16x8 v; } pf;
        pf.u[0] = (unsigned)ra[0]; pf.u[1] = (unsigned)rb[0];
        pf.u[2] = (unsigned)ra[1]; pf.u[3] = (unsigned)rb[1];
        // l += ones * P ; O_T += V_T * P
        l_acc = __builtin_amdgcn_mfma_f32_32x32x16_bf16(ones, pf.v, l_acc, 0, 0, 0);
        int vblk = wt * 16 + tb * 4 + kb * 2 + hi;
        bf16x8 va = *(const bf16x8*)&v_lds[(size_t)l31 * 256 + ((vblk ^ dmask) << 3)];
        o_acc = __builtin_amdgcn_mfma_f32_32x32x16_bf16(va, pf.v, o_acc, 0, 0, 0);
      }
    }
  }
  // combine t-halves: fixed-max softmax partials are pure sums
  __syncthreads();
  if (wt == 1) {
    ored[(wq << 6) + lane] = o_acc;
    lred[(wq << 6) + lane] = l_acc[0];
  }
  __syncthreads();
  if (wt == 0) {
    f32x16 o2 = ored[(wq << 6) + lane];
    float inv_l = 1.0f / (l_acc[0] + lred[(wq << 6) + lane]);
    // O_T[d][q]: col q = l31; rows d = (reg&3) + 8*(reg>>2) + 4*hi
#pragma unroll
    for (int c2 = 0; c2 < 4; c2++) {
      alignas(8) hbf tmp[4];
#pragma unroll
      for (int r = 0; r < 4; r++)
        tmp[r] = __float2bfloat16((o_acc[c2 * 4 + r] + o2[c2 * 4 + r]) * inv_l);
      *(uint2*)&attn_t[((size_t)bt * S_ + qrow) * C_ + h * HD + c2 * 8 + hi * 4] = *(uint2*)tmp;
    }
  }
}

// ---------------- Proj GEMM + bias + residual: out[b][o][s] f32 ----------------
__global__ __launch_bounds__(256) void proj_gemm(const hbf* __restrict__ attn_t, const hbf* __restrict__ wb,
                                                 const float* __restrict__ bias, const float* __restrict__ x,
                                                 float* __restrict__ out) {
  int bt = blockIdx.z;
  int m0 = blockIdx.x * 64;
  int n0 = blockIdx.y * 64;
  const hbf* A = attn_t + (size_t)bt * S_ * C_;
  __shared__ hbf a_lds[64][72];
  __shared__ hbf b_lds[64][72];
  int tid = threadIdx.x, lane = tid & 63, wid = tid >> 6;
  int wm = (wid >> 1) * 32, wn = (wid & 1) * 32;
  f32x4 acc[2][2] = {};
  for (int k0 = 0; k0 < C_; k0 += 64) {
    __syncthreads();
    int r = tid >> 3, kk = (tid & 7) * 8;
#pragma unroll
    for (int p = 0; p < 2; p++) {
      *(bf16x8*)&a_lds[r + p * 32][kk] = *(const bf16x8*)&A[(size_t)(m0 + r + p * 32) * C_ + k0 + kk];
      *(bf16x8*)&b_lds[r + p * 32][kk] = *(const bf16x8*)&wb[(size_t)(n0 + r + p * 32) * C_ + k0 + kk];
    }
    __syncthreads();
#pragma unroll
    for (int kk2 = 0; kk2 < 64; kk2 += 32) {
      bf16x8 af[2], bfr[2];
#pragma unroll
      for (int mi = 0; mi < 2; mi++)
        af[mi] = *(const bf16x8*)&a_lds[wm + mi * 16 + (lane & 15)][kk2 + (lane >> 4) * 8];
#pragma unroll
      for (int ni = 0; ni < 2; ni++)
        bfr[ni] = *(const bf16x8*)&b_lds[wn + ni * 16 + (lane & 15)][kk2 + (lane >> 4) * 8];
#pragma unroll
      for (int mi = 0; mi < 2; mi++)
#pragma unroll
        for (int ni = 0; ni < 2; ni++)
          acc[mi][ni] = __builtin_amdgcn_mfma_f32_16x16x32_bf16(af[mi], bfr[ni], acc[mi][ni], 0, 0, 0);
    }
  }
#pragma unroll
  for (int mi = 0; mi < 2; mi++)
#pragma unroll
    for (int ni = 0; ni < 2; ni++) {
      int o = n0 + wn + ni * 16 + (lane & 15);
      int s = m0 + wm + mi * 16 + (lane >> 4) * 4;
      size_t base = ((size_t)bt * C_ + o) * S_ + s;
      float pb = bias[o];
      float4 xr = *(const float4*)&x[base];
      float4 res;
      res.x = acc[mi][ni][0] + pb + xr.x;
      res.y = acc[mi][ni][1] + pb + xr.y;
      res.z = acc[mi][ni][2] + pb + xr.z;
      res.w = acc[mi][ni][3] + pb + xr.w;
      *(float4*)&out[base] = res;
    }
}

extern "C" void kernel_launch(void* const* d_in, const int* in_sizes, int n_in,
                              void* d_out, int out_size, void* d_ws, size_t ws_size,
                              hipStream_t stream) {
  const float* x = (const float*)d_in[0];
  const float* gn_w = (const float*)d_in[1];
  const float* gn_b = (const float*)d_in[2];
  const float* qkv_w = (const float*)d_in[3];
  const float* qkv_b = (const float*)d_in[4];
  const float* proj_w = (const float*)d_in[5];
  const float* proj_b = (const float*)d_in[6];
  float* out = (float*)d_out;

  hbf* qkv_w_bf = (hbf*)d_ws;                                   // 768*256
  hbf* proj_w_bf = qkv_w_bf + 768 * 256;                        // 256*256
  hbf* xn_t = proj_w_bf + 256 * 256;                            // B*S*C
  hbf* qbuf = xn_t + (size_t)B_ * S_ * C_;                      // B*S*C (q, scaled)
  hbf* kbuf = qbuf + (size_t)B_ * S_ * C_;                      // B*NH*S*HD (k head-contiguous)
  hbf* vbuf = kbuf + (size_t)B_ * S_ * C_;                      // B*C*S (v transposed per head)
  hbf* attn_t = vbuf + (size_t)B_ * C_ * S_;                    // B*S*C

  dim3 blk(256);
  f2bf_kernel<<<(768 * 256 + 255) / 256, blk, 0, stream>>>(qkv_w, qkv_w_bf, 768 * 256);
  f2bf_kernel<<<(256 * 256 + 255) / 256, blk, 0, stream>>>(proj_w, proj_w_bf, 256 * 256);
  gn_kernel<<<64, blk, 0, stream>>>(x, gn_w, gn_b, xn_t);
  qkv_gemm<<<dim3(64, 12, 2), blk, 0, stream>>>(xn_t, qkv_w_bf, qkv_b, qbuf, kbuf, vbuf);
  attn_kernel<<<dim3(32, 8, 2), dim3(512), 0, stream>>>(qbuf, kbuf, vbuf, attn_t);
  proj_gemm<<<dim3(64, 4, 2), blk, 0, stream>>>(attn_t, proj_w_bf, proj_b, x, out);
}

// Round 6
// 143.723 us; speedup vs baseline: 1.1642x; 1.0021x over previous
//
#include <hip/hip_runtime.h>
#include <hip/hip_bf16.h>

#define B_ 2
#define C_ 256
#define S_ 4096
#define NH 8
#define HD 32
#define EPSV 1e-5f
// QSCALE * log2(e): scores computed in log2 units so softmax uses exp2
#define QSC2 0.25503487942324256f

typedef __bf16 bf16_t;
typedef bf16_t bf16x8 __attribute__((ext_vector_type(8)));
typedef float f32x4 __attribute__((ext_vector_type(4)));
typedef float f32x16 __attribute__((ext_vector_type(16)));
typedef int i32x2 __attribute__((ext_vector_type(2)));
typedef __hip_bfloat16 hbf;

__device__ inline unsigned cvtpk_bf16(float a, float b) {
  unsigned r;
  asm("v_cvt_pk_bf16_f32 %0, %1, %2" : "=v"(r) : "v"(a), "v"(b));
  return r;
}

// ---------------- fp32 -> bf16 weight convert ----------------
__global__ __launch_bounds__(256) void f2bf_kernel(const float* __restrict__ src, hbf* __restrict__ dst, int n) {
  int i = blockIdx.x * 256 + threadIdx.x;
  if (i < n) dst[i] = __float2bfloat16(src[i]);
}

// ---------------- GroupNorm + transpose: x[b][c][s] f32 -> xn_t[b][s][c] bf16 ----------------
__global__ __launch_bounds__(256) void gn_kernel(const float* __restrict__ x, const float* __restrict__ gw,
                                                 const float* __restrict__ gb, hbf* __restrict__ xn_t) {
  int b = blockIdx.x >> 5, g = blockIdx.x & 31;
  const float* xp = x + ((size_t)b * C_ + g * 8) * S_;
  float sum = 0.f, sumsq = 0.f;
  const float4* xp4 = (const float4*)xp;
  for (int i = threadIdx.x; i < 8 * S_ / 4; i += 256) {
    float4 v = xp4[i];
    sum += v.x + v.y + v.z + v.w;
    sumsq += v.x * v.x + v.y * v.y + v.z * v.z + v.w * v.w;
  }
#pragma unroll
  for (int off = 32; off > 0; off >>= 1) {
    sum += __shfl_down(sum, off);
    sumsq += __shfl_down(sumsq, off);
  }
  __shared__ float red[2][4];
  int wid = threadIdx.x >> 6;
  if ((threadIdx.x & 63) == 0) { red[0][wid] = sum; red[1][wid] = sumsq; }
  __syncthreads();
  sum = red[0][0] + red[0][1] + red[0][2] + red[0][3];
  sumsq = red[1][0] + red[1][1] + red[1][2] + red[1][3];
  const float inv_n = 1.f / (8 * S_);
  float mean = sum * inv_n;
  float rstd = rsqrtf(fmaxf(sumsq * inv_n - mean * mean, 0.f) + EPSV);
  int c = threadIdx.x & 7;
  float sc = gw[g * 8 + c] * rstd;
  float sh = gb[g * 8 + c] - mean * sc;
  hbf* outp = xn_t + (size_t)b * S_ * C_ + g * 8;
  for (int i = threadIdx.x; i < 8 * S_; i += 256) {
    int s = i >> 3;
    float v = xp[(size_t)c * S_ + s];
    outp[(size_t)s * C_ + c] = __float2bfloat16(v * sc + sh);
  }
}

// ---------------- QKV GEMM (BT-form): D[s][o] = sum_c xn_t[s][c] * W[o][c] + bias ----------------
// o<256: q -> qbuf[b][s][o] scaled by QSC2
// 256<=o<512: k -> kbuf[b][h][t][d] head-contiguous
// o>=512: v -> vbuf[b][o-512][s] (transposed)
__global__ __launch_bounds__(256) void qkv_gemm(const hbf* __restrict__ xn_t, const hbf* __restrict__ wb,
                                                const float* __restrict__ bias,
                                                hbf* __restrict__ qbuf, hbf* __restrict__ kbuf,
                                                hbf* __restrict__ vbuf) {
  int bt = blockIdx.z;
  int m0 = blockIdx.x * 64;
  int n0 = blockIdx.y * 64;
  const hbf* A = xn_t + (size_t)bt * S_ * C_;
  __shared__ hbf a_lds[64][72];
  __shared__ hbf b_lds[64][72];
  int tid = threadIdx.x, lane = tid & 63, wid = tid >> 6;
  int wm = (wid >> 1) * 32, wn = (wid & 1) * 32;
  f32x4 acc[2][2] = {};
  for (int k0 = 0; k0 < C_; k0 += 64) {
    __syncthreads();
    int r = tid >> 3, kk = (tid & 7) * 8;
#pragma unroll
    for (int p = 0; p < 2; p++) {
      *(bf16x8*)&a_lds[r + p * 32][kk] = *(const bf16x8*)&A[(size_t)(m0 + r + p * 32) * C_ + k0 + kk];
      *(bf16x8*)&b_lds[r + p * 32][kk] = *(const bf16x8*)&wb[(size_t)(n0 + r + p * 32) * C_ + k0 + kk];
    }
    __syncthreads();
#pragma unroll
    for (int kk2 = 0; kk2 < 64; kk2 += 32) {
      bf16x8 af[2], bfr[2];
#pragma unroll
      for (int mi = 0; mi < 2; mi++)
        af[mi] = *(const bf16x8*)&a_lds[wm + mi * 16 + (lane & 15)][kk2 + (lane >> 4) * 8];
#pragma unroll
      for (int ni = 0; ni < 2; ni++)
        bfr[ni] = *(const bf16x8*)&b_lds[wn + ni * 16 + (lane & 15)][kk2 + (lane >> 4) * 8];
#pragma unroll
      for (int mi = 0; mi < 2; mi++)
#pragma unroll
        for (int ni = 0; ni < 2; ni++)
          acc[mi][ni] = __builtin_amdgcn_mfma_f32_16x16x32_bf16(af[mi], bfr[ni], acc[mi][ni], 0, 0, 0);
    }
  }
#pragma unroll
  for (int mi = 0; mi < 2; mi++)
#pragma unroll
    for (int ni = 0; ni < 2; ni++) {
      int o = n0 + wn + ni * 16 + (lane & 15);
      int s = m0 + wm + mi * 16 + (lane >> 4) * 4;
      float bs = bias[o];
      f32x4 v = acc[mi][ni];
      if (o < 256) {
#pragma unroll
        for (int rr = 0; rr < 4; rr++)
          qbuf[((size_t)bt * S_ + s + rr) * C_ + o] = __float2bfloat16((v[rr] + bs) * QSC2);
      } else if (o < 512) {
        int hh = (o - 256) >> 5, dd = (o - 256) & 31;
#pragma unroll
        for (int rr = 0; rr < 4; rr++)
          kbuf[((size_t)(bt * NH + hh) * S_ + s + rr) * HD + dd] = __float2bfloat16(v[rr] + bs);
      } else {
        alignas(8) hbf tmp[4];
#pragma unroll
        for (int rr = 0; rr < 4; rr++) tmp[rr] = __float2bfloat16(v[rr] + bs);
        *(uint2*)&vbuf[((size_t)bt * C_ + (o - 512)) * S_ + s] = *(uint2*)tmp;
      }
    }
}

// ---------------- Flash attention v6: occupancy-first (2q x 4t waves, 32KB LDS, scalar l) ----------------
// Block: 512 threads, 8 waves = 2 q-subtiles(32 rows) x 4 t-quarters. 256-t super-tile/iter.
// Swapped QK (sc = D[t][q]), fixed-max exp2, in-register P (cvt_pk + permlane32_swap),
// PV swapped (A = V_T). l = scalar VALU sum (frees AGPRs). 4 t-partials combined via LDS overlay.
__global__ __launch_bounds__(512, 6) void attn_kernel(const hbf* __restrict__ qbuf, const hbf* __restrict__ kbuf,
                                                      const hbf* __restrict__ vbuf, hbf* __restrict__ attn_t) {
  int bt = blockIdx.z, h = blockIdx.y;
  int s0 = blockIdx.x * 64;
  const hbf* kbh = kbuf + (size_t)(bt * NH + h) * S_ * HD;
  const hbf* vb = vbuf + ((size_t)bt * C_ + h * HD) * S_;
  int tid = threadIdx.x, lane = tid & 63, w = tid >> 6;
  int wq = w & 1, wt = w >> 1;
  int l31 = lane & 31, hi = lane >> 5;
  __shared__ char smem[32768];
  hbf* k_lds = (hbf*)smem;            // K[t][d]: 256 x 32 (64B rows), 16B-block c ^= (t&3)   [16KB]
  hbf* v_lds = (hbf*)(smem + 16384);  // V_T[d][t]: 32 x 256 (512B rows), 16B-block c ^= (d&7) [16KB]
  // Q B-frags: lane holds Q[q = l31][d = kk*16 + hi*8 + j]  (q pre-scaled by QSC2)
  int qrow = s0 + wq * 32 + l31;
  bf16x8 qf0 = *(const bf16x8*)&qbuf[((size_t)bt * S_ + qrow) * C_ + h * HD + hi * 8];
  bf16x8 qf1 = *(const bf16x8*)&qbuf[((size_t)bt * S_ + qrow) * C_ + h * HD + 16 + hi * 8];
  f32x16 o_acc = {0.f,0.f,0.f,0.f,0.f,0.f,0.f,0.f,0.f,0.f,0.f,0.f,0.f,0.f,0.f,0.f};
  const f32x16 z16 = o_acc;
  float l_run = 0.f;
  const int m3 = l31 & 3;   // K-row swizzle phase (row & 3 == l31 & 3 for our t's)
  const int m7 = l31 & 7;   // V-row swizzle phase (d == l31)
  for (int t0 = 0; t0 < S_; t0 += 256) {
    __syncthreads();
    // stage K: 256 rows x 32 d -> [256][32], block c ^= (r&3); contiguous global stream
#pragma unroll
    for (int p = 0; p < 2; p++) {
      int ci = tid + (p << 9);
      int r = ci >> 2, c = ci & 3;
      *(bf16x8*)&k_lds[(size_t)r * 32 + ((c ^ (r & 3)) << 3)] =
          *(const bf16x8*)&kbh[(size_t)(t0 + r) * HD + (c << 3)];
    }
    // stage V_T: 32 rows x 256 t -> [32][256], block c ^= (d&7); coalesced
#pragma unroll
    for (int p = 0; p < 2; p++) {
      int ci = tid + (p << 9);
      int d = ci >> 5, c = ci & 31;
      *(bf16x8*)&v_lds[(size_t)d * 256 + ((c ^ (d & 7)) << 3)] =
          *(const bf16x8*)&vb[(size_t)d * S_ + t0 + (c << 3)];
    }
    __syncthreads();
#pragma unroll
    for (int tb = 0; tb < 2; tb++) {
      int t = (wt << 6) + (tb << 5) + l31;
      // QK^T swapped: sc = D[t][q], A = K[t][k], B = Q (2 chained k-blocks over d=32)
      bf16x8 ka0 = *(const bf16x8*)&k_lds[(size_t)t * 32 + ((hi ^ m3) << 3)];
      bf16x8 ka1 = *(const bf16x8*)&k_lds[(size_t)t * 32 + (((2 + hi) ^ m3) << 3)];
      f32x16 sc = __builtin_amdgcn_mfma_f32_32x32x16_bf16(ka0, qf0, z16, 0, 0, 0);
      sc = __builtin_amdgcn_mfma_f32_32x32x16_bf16(ka1, qf1, sc, 0, 0, 0);
      // fixed-max softmax numerator: p = exp2(sc); l accumulated as scalar
      float ls = 0.f;
#pragma unroll
      for (int i = 0; i < 16; i++) { sc[i] = exp2f(sc[i]); ls += sc[i]; }
      l_run += ls;
      // C-frag -> B-frag in registers: per 16-t block kb: 4 cvt_pk + 2 permlane32_swap
#pragma unroll
      for (int kb = 0; kb < 2; kb++) {
        unsigned a0 = cvtpk_bf16(sc[kb * 8 + 0], sc[kb * 8 + 1]);
        unsigned b0 = cvtpk_bf16(sc[kb * 8 + 2], sc[kb * 8 + 3]);
        unsigned a1 = cvtpk_bf16(sc[kb * 8 + 4], sc[kb * 8 + 5]);
        unsigned b1 = cvtpk_bf16(sc[kb * 8 + 6], sc[kb * 8 + 7]);
        i32x2 ra = __builtin_amdgcn_permlane32_swap((int)a0, (int)a1, false, false);
        i32x2 rb = __builtin_amdgcn_permlane32_swap((int)b0, (int)b1, false, false);
        union { unsigned u[4]; bf16x8 v; } pf;
        pf.u[0] = (unsigned)ra[0]; pf.u[1] = (unsigned)rb[0];
        pf.u[2] = (unsigned)ra[1]; pf.u[3] = (unsigned)rb[1];
        // O_T += V_T * P ; V A-frag: row d = l31, t-block j = tb*4 + kb*2 + hi within quarter wt
        int j = (tb << 2) + (kb << 1) + hi;
        bf16x8 va = *(const bf16x8*)&v_lds[(size_t)l31 * 256 + (((wt << 3) + (j ^ m7)) << 3)];
        o_acc = __builtin_amdgcn_mfma_f32_32x32x16_bf16(va, pf.v, o_acc, 0, 0, 0);
      }
    }
  }
  // combine the 4 t-quarter partials (pure sums under fixed-max softmax)
  __syncthreads();
  f32x16* ored = (f32x16*)smem;            // waves 2..7: 6*64*64B = 24KB
  float* lred = (float*)(smem + 24576);    // all 8 waves: 8*64*4B = 2KB
  lred[(w << 6) + lane] = l_run;
  if (wt > 0) ored[((w - 2) << 6) + lane] = o_acc;
  __syncthreads();
  if (wt == 0) {
    float l_tot = 0.f;
#pragma unroll
    for (int k = 0; k < 4; k++) {
      int wp = wq + 2 * k;
      l_tot += lred[(wp << 6) + l31] + lred[(wp << 6) + 32 + l31];
    }
    f32x16 o = o_acc;
#pragma unroll
    for (int k = 0; k < 3; k++) {
      f32x16 t2 = ored[((wq + 2 * k) << 6) + lane];
#pragma unroll
      for (int i = 0; i < 16; i++) o[i] += t2[i];
    }
    float inv_l = 1.0f / l_tot;
    // O_T[d][q]: col q = l31; rows d = (reg&3) + 8*(reg>>2) + 4*hi
#pragma unroll
    for (int c2 = 0; c2 < 4; c2++) {
      alignas(8) hbf tmp[4];
#pragma unroll
      for (int r = 0; r < 4; r++) tmp[r] = __float2bfloat16(o[c2 * 4 + r] * inv_l);
      *(uint2*)&attn_t[((size_t)bt * S_ + qrow) * C_ + h * HD + c2 * 8 + hi * 4] = *(uint2*)tmp;
    }
  }
}

// ---------------- Proj GEMM + bias + residual: out[b][o][s] f32 ----------------
__global__ __launch_bounds__(256) void proj_gemm(const hbf* __restrict__ attn_t, const hbf* __restrict__ wb,
                                                 const float* __restrict__ bias, const float* __restrict__ x,
                                                 float* __restrict__ out) {
  int bt = blockIdx.z;
  int m0 = blockIdx.x * 64;
  int n0 = blockIdx.y * 64;
  const hbf* A = attn_t + (size_t)bt * S_ * C_;
  __shared__ hbf a_lds[64][72];
  __shared__ hbf b_lds[64][72];
  int tid = threadIdx.x, lane = tid & 63, wid = tid >> 6;
  int wm = (wid >> 1) * 32, wn = (wid & 1) * 32;
  f32x4 acc[2][2] = {};
  for (int k0 = 0; k0 < C_; k0 += 64) {
    __syncthreads();
    int r = tid >> 3, kk = (tid & 7) * 8;
#pragma unroll
    for (int p = 0; p < 2; p++) {
      *(bf16x8*)&a_lds[r + p * 32][kk] = *(const bf16x8*)&A[(size_t)(m0 + r + p * 32) * C_ + k0 + kk];
      *(bf16x8*)&b_lds[r + p * 32][kk] = *(const bf16x8*)&wb[(size_t)(n0 + r + p * 32) * C_ + k0 + kk];
    }
    __syncthreads();
#pragma unroll
    for (int kk2 = 0; kk2 < 64; kk2 += 32) {
      bf16x8 af[2], bfr[2];
#pragma unroll
      for (int mi = 0; mi < 2; mi++)
        af[mi] = *(const bf16x8*)&a_lds[wm + mi * 16 + (lane & 15)][kk2 + (lane >> 4) * 8];
#pragma unroll
      for (int ni = 0; ni < 2; ni++)
        bfr[ni] = *(const bf16x8*)&b_lds[wn + ni * 16 + (lane & 15)][kk2 + (lane >> 4) * 8];
#pragma unroll
      for (int mi = 0; mi < 2; mi++)
#pragma unroll
        for (int ni = 0; ni < 2; ni++)
          acc[mi][ni] = __builtin_amdgcn_mfma_f32_16x16x32_bf16(af[mi], bfr[ni], acc[mi][ni], 0, 0, 0);
    }
  }
#pragma unroll
  for (int mi = 0; mi < 2; mi++)
#pragma unroll
    for (int ni = 0; ni < 2; ni++) {
      int o = n0 + wn + ni * 16 + (lane & 15);
      int s = m0 + wm + mi * 16 + (lane >> 4) * 4;
      size_t base = ((size_t)bt * C_ + o) * S_ + s;
      float pb = bias[o];
      float4 xr = *(const float4*)&x[base];
      float4 res;
      res.x = acc[mi][ni][0] + pb + xr.x;
      res.y = acc[mi][ni][1] + pb + xr.y;
      res.z = acc[mi][ni][2] + pb + xr.z;
      res.w = acc[mi][ni][3] + pb + xr.w;
      *(float4*)&out[base] = res;
    }
}

extern "C" void kernel_launch(void* const* d_in, const int* in_sizes, int n_in,
                              void* d_out, int out_size, void* d_ws, size_t ws_size,
                              hipStream_t stream) {
  const float* x = (const float*)d_in[0];
  const float* gn_w = (const float*)d_in[1];
  const float* gn_b = (const float*)d_in[2];
  const float* qkv_w = (const float*)d_in[3];
  const float* qkv_b = (const float*)d_in[4];
  const float* proj_w = (const float*)d_in[5];
  const float* proj_b = (const float*)d_in[6];
  float* out = (float*)d_out;

  hbf* qkv_w_bf = (hbf*)d_ws;                                   // 768*256
  hbf* proj_w_bf = qkv_w_bf + 768 * 256;                        // 256*256
  hbf* xn_t = proj_w_bf + 256 * 256;                            // B*S*C
  hbf* qbuf = xn_t + (size_t)B_ * S_ * C_;                      // B*S*C (q, scaled)
  hbf* kbuf = qbuf + (size_t)B_ * S_ * C_;                      // B*NH*S*HD (k head-contiguous)
  hbf* vbuf = kbuf + (size_t)B_ * S_ * C_;                      // B*C*S (v transposed per head)
  hbf* attn_t = vbuf + (size_t)B_ * C_ * S_;                    // B*S*C

  dim3 blk(256);
  f2bf_kernel<<<(768 * 256 + 255) / 256, blk, 0, stream>>>(qkv_w, qkv_w_bf, 768 * 256);
  f2bf_kernel<<<(256 * 256 + 255) / 256, blk, 0, stream>>>(proj_w, proj_w_bf, 256 * 256);
  gn_kernel<<<64, blk, 0, stream>>>(x, gn_w, gn_b, xn_t);
  qkv_gemm<<<dim3(64, 12, 2), blk, 0, stream>>>(xn_t, qkv_w_bf, qkv_b, qbuf, kbuf, vbuf);
  attn_kernel<<<dim3(64, 8, 2), dim3(512), 0, stream>>>(qbuf, kbuf, vbuf, attn_t);
  proj_gemm<<<dim3(64, 4, 2), blk, 0, stream>>>(attn_t, proj_w_bf, proj_b, x, out);
}

// Round 7
// 127.718 us; speedup vs baseline: 1.3101x; 1.1253x over previous
//
#include <hip/hip_runtime.h>
#include <hip/hip_bf16.h>

#define B_ 2
#define C_ 256
#define S_ 4096
#define NH 8
#define HD 32
#define EPSV 1e-5f
// QSCALE * log2(e): scores computed in log2 units so softmax uses exp2
#define QSC2 0.25503487942324256f

typedef __bf16 bf16_t;
typedef bf16_t bf16x8 __attribute__((ext_vector_type(8)));
typedef float f32x4 __attribute__((ext_vector_type(4)));
typedef float f32x16 __attribute__((ext_vector_type(16)));
typedef int i32x2 __attribute__((ext_vector_type(2)));
typedef __hip_bfloat16 hbf;

__device__ inline unsigned cvtpk_bf16(float a, float b) {
  unsigned r;
  asm("v_cvt_pk_bf16_f32 %0, %1, %2" : "=v"(r) : "v"(a), "v"(b));
  return r;
}

// ---------------- fp32 -> bf16 weight convert ----------------
__global__ __launch_bounds__(256) void f2bf_kernel(const float* __restrict__ src, hbf* __restrict__ dst, int n) {
  int i = blockIdx.x * 256 + threadIdx.x;
  if (i < n) dst[i] = __float2bfloat16(src[i]);
}

// ---------------- GroupNorm + transpose: x[b][c][s] f32 -> xn_t[b][s][c] bf16 ----------------
__global__ __launch_bounds__(256) void gn_kernel(const float* __restrict__ x, const float* __restrict__ gw,
                                                 const float* __restrict__ gb, hbf* __restrict__ xn_t) {
  int b = blockIdx.x >> 5, g = blockIdx.x & 31;
  const float* xp = x + ((size_t)b * C_ + g * 8) * S_;
  float sum = 0.f, sumsq = 0.f;
  const float4* xp4 = (const float4*)xp;
  for (int i = threadIdx.x; i < 8 * S_ / 4; i += 256) {
    float4 v = xp4[i];
    sum += v.x + v.y + v.z + v.w;
    sumsq += v.x * v.x + v.y * v.y + v.z * v.z + v.w * v.w;
  }
#pragma unroll
  for (int off = 32; off > 0; off >>= 1) {
    sum += __shfl_down(sum, off);
    sumsq += __shfl_down(sumsq, off);
  }
  __shared__ float red[2][4];
  int wid = threadIdx.x >> 6;
  if ((threadIdx.x & 63) == 0) { red[0][wid] = sum; red[1][wid] = sumsq; }
  __syncthreads();
  sum = red[0][0] + red[0][1] + red[0][2] + red[0][3];
  sumsq = red[1][0] + red[1][1] + red[1][2] + red[1][3];
  const float inv_n = 1.f / (8 * S_);
  float mean = sum * inv_n;
  float rstd = rsqrtf(fmaxf(sumsq * inv_n - mean * mean, 0.f) + EPSV);
  int c = threadIdx.x & 7;
  float sc = gw[g * 8 + c] * rstd;
  float sh = gb[g * 8 + c] - mean * sc;
  hbf* outp = xn_t + (size_t)b * S_ * C_ + g * 8;
  for (int i = threadIdx.x; i < 8 * S_; i += 256) {
    int s = i >> 3;
    float v = xp[(size_t)c * S_ + s];
    outp[(size_t)s * C_ + c] = __float2bfloat16(v * sc + sh);
  }
}

// ---------------- QKV GEMM (BT-form): D[s][o] = sum_c xn_t[s][c] * W[o][c] + bias ----------------
// o<256: q -> qbuf[b][s][o] scaled by QSC2
// 256<=o<512: k -> kbuf[b][h][t][d] head-contiguous
// o>=512: v -> vg[b][h][t/16][d][t%16]  fragment-major (direct PV A-frag loads)
__global__ __launch_bounds__(256) void qkv_gemm(const hbf* __restrict__ xn_t, const hbf* __restrict__ wb,
                                                const float* __restrict__ bias,
                                                hbf* __restrict__ qbuf, hbf* __restrict__ kbuf,
                                                hbf* __restrict__ vg) {
  int bt = blockIdx.z;
  int m0 = blockIdx.x * 64;
  int n0 = blockIdx.y * 64;
  const hbf* A = xn_t + (size_t)bt * S_ * C_;
  __shared__ hbf a_lds[64][72];
  __shared__ hbf b_lds[64][72];
  int tid = threadIdx.x, lane = tid & 63, wid = tid >> 6;
  int wm = (wid >> 1) * 32, wn = (wid & 1) * 32;
  f32x4 acc[2][2] = {};
  for (int k0 = 0; k0 < C_; k0 += 64) {
    __syncthreads();
    int r = tid >> 3, kk = (tid & 7) * 8;
#pragma unroll
    for (int p = 0; p < 2; p++) {
      *(bf16x8*)&a_lds[r + p * 32][kk] = *(const bf16x8*)&A[(size_t)(m0 + r + p * 32) * C_ + k0 + kk];
      *(bf16x8*)&b_lds[r + p * 32][kk] = *(const bf16x8*)&wb[(size_t)(n0 + r + p * 32) * C_ + k0 + kk];
    }
    __syncthreads();
#pragma unroll
    for (int kk2 = 0; kk2 < 64; kk2 += 32) {
      bf16x8 af[2], bfr[2];
#pragma unroll
      for (int mi = 0; mi < 2; mi++)
        af[mi] = *(const bf16x8*)&a_lds[wm + mi * 16 + (lane & 15)][kk2 + (lane >> 4) * 8];
#pragma unroll
      for (int ni = 0; ni < 2; ni++)
        bfr[ni] = *(const bf16x8*)&b_lds[wn + ni * 16 + (lane & 15)][kk2 + (lane >> 4) * 8];
#pragma unroll
      for (int mi = 0; mi < 2; mi++)
#pragma unroll
        for (int ni = 0; ni < 2; ni++)
          acc[mi][ni] = __builtin_amdgcn_mfma_f32_16x16x32_bf16(af[mi], bfr[ni], acc[mi][ni], 0, 0, 0);
    }
  }
#pragma unroll
  for (int mi = 0; mi < 2; mi++)
#pragma unroll
    for (int ni = 0; ni < 2; ni++) {
      int o = n0 + wn + ni * 16 + (lane & 15);
      int s = m0 + wm + mi * 16 + (lane >> 4) * 4;
      float bs = bias[o];
      f32x4 v = acc[mi][ni];
      if (o < 256) {
#pragma unroll
        for (int rr = 0; rr < 4; rr++)
          qbuf[((size_t)bt * S_ + s + rr) * C_ + o] = __float2bfloat16((v[rr] + bs) * QSC2);
      } else if (o < 512) {
        int hh = (o - 256) >> 5, dd = (o - 256) & 31;
#pragma unroll
        for (int rr = 0; rr < 4; rr++)
          kbuf[((size_t)(bt * NH + hh) * S_ + s + rr) * HD + dd] = __float2bfloat16(v[rr] + bs);
      } else {
        int hh = (o - 512) >> 5, dd = (o - 512) & 31;
        alignas(8) hbf tmp[4];
#pragma unroll
        for (int rr = 0; rr < 4; rr++) tmp[rr] = __float2bfloat16(v[rr] + bs);
        // vg[bt][hh][s/16][dd][s%16]; s%16 in {0,4,8,12} so 4 elems stay in one chunk
        *(uint2*)&vg[(((size_t)(bt * NH + hh) * (S_ >> 4) + (s >> 4)) * 32 + dd) * 16 + (s & 15)] = *(uint2*)tmp;
      }
    }
}

// ---------------- Flash attention v7: LDS-free main loop, direct global MFMA fragments ----------------
// Block: 512 threads, 8 waves = 2 q-subtiles(32 rows) x 4 t-quarters(1024 t each).
// Swapped QK (sc = D[t][q], A-frag = K rows read straight from kbuf, coalesced 2KB/wave),
// fixed-max exp2 softmax, in-register P (cvt_pk + permlane32_swap),
// PV swapped (A-frag = V read straight from fragment-major vg, coalesced 1KB/wave).
// No __shared__ in main loop -> no barriers, no staging, no bank conflicts.
// XCD swizzle: all 64 blocks of one (bt,h) on one XCD -> K/V L2-resident per XCD.
__global__ __launch_bounds__(512, 6) void attn_kernel(const hbf* __restrict__ qbuf, const hbf* __restrict__ kbuf,
                                                      const hbf* __restrict__ vg, hbf* __restrict__ attn_t) {
  int bid = blockIdx.x;
  int xcd = bid & 7, idx = bid >> 3;
  int combo = (xcd << 1) | (idx >> 6);   // 16 combos; 2 per XCD
  int bt = combo >> 3, h = combo & 7;
  int s0 = (idx & 63) << 6;
  const hbf* kbh = kbuf + (size_t)(bt * NH + h) * S_ * HD;
  const hbf* vgh = vg + (size_t)(bt * NH + h) * S_ * 32;
  int tid = threadIdx.x, lane = tid & 63, w = tid >> 6;
  int wq = w & 1, wt = w >> 1;
  int l31 = lane & 31, hi = lane >> 5;
  // Q B-frags: lane holds Q[q = l31][k = hi*8 + j] per 16-k chain (pre-scaled by QSC2)
  int qrow = s0 + wq * 32 + l31;
  bf16x8 qf0 = *(const bf16x8*)&qbuf[((size_t)bt * S_ + qrow) * C_ + h * HD + hi * 8];
  bf16x8 qf1 = *(const bf16x8*)&qbuf[((size_t)bt * S_ + qrow) * C_ + h * HD + 16 + hi * 8];
  f32x16 o_acc = {0.f,0.f,0.f,0.f,0.f,0.f,0.f,0.f,0.f,0.f,0.f,0.f,0.f,0.f,0.f,0.f};
  const f32x16 z16 = o_acc;
  float l_run = 0.f;
  const int tq0 = wt << 10;  // this wave's t-quarter base
  // prologue: K A-frag for tb=0
  bf16x8 ka0 = *(const bf16x8*)&kbh[(size_t)(tq0 + l31) * HD + (hi << 3)];
  bf16x8 ka1 = *(const bf16x8*)&kbh[(size_t)(tq0 + l31) * HD + 16 + (hi << 3)];
  for (int tb = 0; tb < 32; ++tb) {
    int t32 = tq0 + (tb << 5);
    // issue V A-frag loads early (used after the exp2 stretch)
    int cidx = t32 >> 4;
    bf16x8 va0 = *(const bf16x8*)&vgh[((size_t)cidx * 32 + l31) * 16 + (hi << 3)];
    bf16x8 va1 = *(const bf16x8*)&vgh[((size_t)(cidx + 1) * 32 + l31) * 16 + (hi << 3)];
    // depth-1 prefetch of next K A-frag
    int t32n = t32 + ((tb == 31) ? 0 : 32);
    bf16x8 kan0 = *(const bf16x8*)&kbh[(size_t)(t32n + l31) * HD + (hi << 3)];
    bf16x8 kan1 = *(const bf16x8*)&kbh[(size_t)(t32n + l31) * HD + 16 + (hi << 3)];
    // QK^T swapped: sc = D[t][q]
    f32x16 sc = __builtin_amdgcn_mfma_f32_32x32x16_bf16(ka0, qf0, z16, 0, 0, 0);
    sc = __builtin_amdgcn_mfma_f32_32x32x16_bf16(ka1, qf1, sc, 0, 0, 0);
    // fixed-max softmax numerator: p = exp2(sc); l accumulated as scalar
    float ls = 0.f;
#pragma unroll
    for (int i = 0; i < 16; i++) { sc[i] = exp2f(sc[i]); ls += sc[i]; }
    l_run += ls;
    // C-frag -> B-frag in registers: per 16-t half kb: 4 cvt_pk + 2 permlane32_swap
#pragma unroll
    for (int kb = 0; kb < 2; kb++) {
      unsigned a0 = cvtpk_bf16(sc[kb * 8 + 0], sc[kb * 8 + 1]);
      unsigned b0 = cvtpk_bf16(sc[kb * 8 + 2], sc[kb * 8 + 3]);
      unsigned a1 = cvtpk_bf16(sc[kb * 8 + 4], sc[kb * 8 + 5]);
      unsigned b1 = cvtpk_bf16(sc[kb * 8 + 6], sc[kb * 8 + 7]);
      i32x2 ra = __builtin_amdgcn_permlane32_swap((int)a0, (int)a1, false, false);
      i32x2 rb = __builtin_amdgcn_permlane32_swap((int)b0, (int)b1, false, false);
      union { unsigned u[4]; bf16x8 v; } pf;
      pf.u[0] = (unsigned)ra[0]; pf.u[1] = (unsigned)rb[0];
      pf.u[2] = (unsigned)ra[1]; pf.u[3] = (unsigned)rb[1];
      o_acc = __builtin_amdgcn_mfma_f32_32x32x16_bf16(kb ? va1 : va0, pf.v, o_acc, 0, 0, 0);
    }
    ka0 = kan0; ka1 = kan1;
  }
  // combine the 4 t-quarter partials (pure sums under fixed-max softmax)
  __shared__ f32x16 ored[6 * 64];   // waves 2..7 park their o_acc   [24KB]
  __shared__ float lred[8 * 64];    // all 8 waves' l                [2KB]
  __syncthreads();
  lred[(w << 6) + lane] = l_run;
  if (wt > 0) ored[((w - 2) << 6) + lane] = o_acc;
  __syncthreads();
  if (wt == 0) {
    float l_tot = 0.f;
#pragma unroll
    for (int k = 0; k < 4; k++) {
      int wp = wq + 2 * k;
      l_tot += lred[(wp << 6) + l31] + lred[(wp << 6) + 32 + l31];
    }
    f32x16 o = o_acc;
#pragma unroll
    for (int k = 0; k < 3; k++) {
      f32x16 t2 = ored[((wq + 2 * k) << 6) + lane];
#pragma unroll
      for (int i = 0; i < 16; i++) o[i] += t2[i];
    }
    float inv_l = 1.0f / l_tot;
    // O_T[d][q]: col q = l31; rows d = (reg&3) + 8*(reg>>2) + 4*hi
#pragma unroll
    for (int c2 = 0; c2 < 4; c2++) {
      alignas(8) hbf tmp[4];
#pragma unroll
      for (int r = 0; r < 4; r++) tmp[r] = __float2bfloat16(o[c2 * 4 + r] * inv_l);
      *(uint2*)&attn_t[((size_t)bt * S_ + qrow) * C_ + h * HD + c2 * 8 + hi * 4] = *(uint2*)tmp;
    }
  }
}

// ---------------- Proj GEMM + bias + residual: out[b][o][s] f32 ----------------
__global__ __launch_bounds__(256) void proj_gemm(const hbf* __restrict__ attn_t, const hbf* __restrict__ wb,
                                                 const float* __restrict__ bias, const float* __restrict__ x,
                                                 float* __restrict__ out) {
  int bt = blockIdx.z;
  int m0 = blockIdx.x * 64;
  int n0 = blockIdx.y * 64;
  const hbf* A = attn_t + (size_t)bt * S_ * C_;
  __shared__ hbf a_lds[64][72];
  __shared__ hbf b_lds[64][72];
  int tid = threadIdx.x, lane = tid & 63, wid = tid >> 6;
  int wm = (wid >> 1) * 32, wn = (wid & 1) * 32;
  f32x4 acc[2][2] = {};
  for (int k0 = 0; k0 < C_; k0 += 64) {
    __syncthreads();
    int r = tid >> 3, kk = (tid & 7) * 8;
#pragma unroll
    for (int p = 0; p < 2; p++) {
      *(bf16x8*)&a_lds[r + p * 32][kk] = *(const bf16x8*)&A[(size_t)(m0 + r + p * 32) * C_ + k0 + kk];
      *(bf16x8*)&b_lds[r + p * 32][kk] = *(const bf16x8*)&wb[(size_t)(n0 + r + p * 32) * C_ + k0 + kk];
    }
    __syncthreads();
#pragma unroll
    for (int kk2 = 0; kk2 < 64; kk2 += 32) {
      bf16x8 af[2], bfr[2];
#pragma unroll
      for (int mi = 0; mi < 2; mi++)
        af[mi] = *(const bf16x8*)&a_lds[wm + mi * 16 + (lane & 15)][kk2 + (lane >> 4) * 8];
#pragma unroll
      for (int ni = 0; ni < 2; ni++)
        bfr[ni] = *(const bf16x8*)&b_lds[wn + ni * 16 + (lane & 15)][kk2 + (lane >> 4) * 8];
#pragma unroll
      for (int mi = 0; mi < 2; mi++)
#pragma unroll
        for (int ni = 0; ni < 2; ni++)
          acc[mi][ni] = __builtin_amdgcn_mfma_f32_16x16x32_bf16(af[mi], bfr[ni], acc[mi][ni], 0, 0, 0);
    }
  }
#pragma unroll
  for (int mi = 0; mi < 2; mi++)
#pragma unroll
    for (int ni = 0; ni < 2; ni++) {
      int o = n0 + wn + ni * 16 + (lane & 15);
      int s = m0 + wm + mi * 16 + (lane >> 4) * 4;
      size_t base = ((size_t)bt * C_ + o) * S_ + s;
      float pb = bias[o];
      float4 xr = *(const float4*)&x[base];
      float4 res;
      res.x = acc[mi][ni][0] + pb + xr.x;
      res.y = acc[mi][ni][1] + pb + xr.y;
      res.z = acc[mi][ni][2] + pb + xr.z;
      res.w = acc[mi][ni][3] + pb + xr.w;
      *(float4*)&out[base] = res;
    }
}

extern "C" void kernel_launch(void* const* d_in, const int* in_sizes, int n_in,
                              void* d_out, int out_size, void* d_ws, size_t ws_size,
                              hipStream_t stream) {
  const float* x = (const float*)d_in[0];
  const float* gn_w = (const float*)d_in[1];
  const float* gn_b = (const float*)d_in[2];
  const float* qkv_w = (const float*)d_in[3];
  const float* qkv_b = (const float*)d_in[4];
  const float* proj_w = (const float*)d_in[5];
  const float* proj_b = (const float*)d_in[6];
  float* out = (float*)d_out;

  hbf* qkv_w_bf = (hbf*)d_ws;                                   // 768*256
  hbf* proj_w_bf = qkv_w_bf + 768 * 256;                        // 256*256
  hbf* xn_t = proj_w_bf + 256 * 256;                            // B*S*C
  hbf* qbuf = xn_t + (size_t)B_ * S_ * C_;                      // B*S*C (q, scaled)
  hbf* kbuf = qbuf + (size_t)B_ * S_ * C_;                      // B*NH*S*HD (k head-contiguous)
  hbf* vg = kbuf + (size_t)B_ * S_ * C_;                        // B*NH*(S/16)*32*16 (v fragment-major)
  hbf* attn_t = vg + (size_t)B_ * S_ * C_;                      // B*S*C

  dim3 blk(256);
  f2bf_kernel<<<(768 * 256 + 255) / 256, blk, 0, stream>>>(qkv_w, qkv_w_bf, 768 * 256);
  f2bf_kernel<<<(256 * 256 + 255) / 256, blk, 0, stream>>>(proj_w, proj_w_bf, 256 * 256);
  gn_kernel<<<64, blk, 0, stream>>>(x, gn_w, gn_b, xn_t);
  qkv_gemm<<<dim3(64, 12, 2), blk, 0, stream>>>(xn_t, qkv_w_bf, qkv_b, qbuf, kbuf, vg);
  attn_kernel<<<dim3(1024), dim3(512), 0, stream>>>(qbuf, kbuf, vg, attn_t);
  proj_gemm<<<dim3(64, 4, 2), blk, 0, stream>>>(attn_t, proj_w_bf, proj_b, x, out);
}